// Round 4
// baseline (306.819 us; speedup 1.0000x reference)
//
#include <hip/hip_runtime.h>
#include <hip/hip_bf16.h>

#define NN   4096
#define IND  512
#define HIDD 64
#define OUTD 8
#define NH   2
#define CAP  128

using bf16 = __hip_bfloat16;

__device__ __forceinline__ float b2f(bf16 v) { return __bfloat162float(v); }

// adj diagonal is all ones. word0: fp32 -> 1.0f (low16==0); bf16 -> low16==0x3F80.
__device__ __forceinline__ bool sniff_bf(const unsigned* __restrict__ adjw) {
    return (adjw[0] & 0xFFFFu) == 0x3F80u;
}
__device__ __forceinline__ float ldf(const void* p, int i, bool isbf) {
    return isbf ? b2f(((const bf16*)p)[i]) : ((const float*)p)[i];
}
// load 8 consecutive elements (16B-aligned offset) as fp32
__device__ __forceinline__ void load8f(const void* p, size_t off, bool isbf, float* o) {
    if (isbf) {
        uint4 d = *reinterpret_cast<const uint4*>((const bf16*)p + off);
        unsigned u[4] = {d.x, d.y, d.z, d.w};
#pragma unroll
        for (int w = 0; w < 4; ++w) {
            o[2 * w]     = __uint_as_float(u[w] << 16);
            o[2 * w + 1] = __uint_as_float(u[w] & 0xFFFF0000u);
        }
    } else {
        const float* q = (const float*)p + off;
        float4 a = *reinterpret_cast<const float4*>(q);
        float4 b = *reinterpret_cast<const float4*>(q + 4);
        o[0] = a.x; o[1] = a.y; o[2] = a.z; o[3] = a.w;
        o[4] = b.x; o[5] = b.y; o[6] = b.z; o[7] = b.w;
    }
}

// ---------- h @ W1 : [64 x 512] * [512 x 64] ----------
template <typename T>
__device__ __forceinline__ void hw_body(const T* __restrict__ A,
                                        const T* __restrict__ B,
                                        float* __restrict__ C, int i0,
                                        float (*As)[68], float (*Bs)[68]) {
    int tid = threadIdx.x;
    int r0 = (tid >> 4) * 4;
    int c0 = (tid & 15) * 4;
    float acc[4][4] = {};
    for (int kc = 0; kc < IND; kc += 32) {
        {   // stage A: 64 rows x 32 k
            int row = tid >> 2;
            int kp  = (tid & 3) * 8;
            float t8[8];
            load8f((const void*)A, (size_t)(i0 + row) * IND + kc + kp, sizeof(T) == 2, t8);
#pragma unroll
            for (int j = 0; j < 8; ++j) As[kp + j][row] = t8[j];
        }
        {   // stage B: 32 k x 64 cols
            int kb = tid >> 3;
            int cp = (tid & 7) * 8;
            float t8[8];
            load8f((const void*)B, (size_t)(kc + kb) * HIDD + cp, sizeof(T) == 2, t8);
#pragma unroll
            for (int j = 0; j < 8; ++j) Bs[kb][cp + j] = t8[j];
        }
        __syncthreads();
#pragma unroll 8
        for (int k = 0; k < 32; ++k) {
            float4 av = *reinterpret_cast<const float4*>(&As[k][r0]);
            float4 bv = *reinterpret_cast<const float4*>(&Bs[k][c0]);
            float aa[4] = {av.x, av.y, av.z, av.w};
            float bb[4] = {bv.x, bv.y, bv.z, bv.w};
#pragma unroll
            for (int ia = 0; ia < 4; ++ia)
#pragma unroll
                for (int ib = 0; ib < 4; ++ib)
                    acc[ia][ib] = fmaf(aa[ia], bb[ib], acc[ia][ib]);
        }
        __syncthreads();
    }
#pragma unroll
    for (int ia = 0; ia < 4; ++ia)
        *reinterpret_cast<float4*>(C + (size_t)(i0 + r0 + ia) * HIDD + c0) =
            make_float4(acc[ia][0], acc[ia][1], acc[ia][2], acc[ia][3]);
}

// ---------- K1: blocks [0,128) compute hW tiles; blocks [128,8320) build CSR ----------
__global__ void __launch_bounds__(256) k1_csr_hw(const void* __restrict__ h,
                                                 const void* __restrict__ W1,
                                                 const void* __restrict__ adjv,
                                                 int* __restrict__ deg,
                                                 int* __restrict__ cols,
                                                 float* __restrict__ hW,
                                                 float* __restrict__ vsum) {
    __shared__ __align__(16) float As[32][68];
    __shared__ __align__(16) float Bs[32][68];
    __shared__ int s_cnt;
    __shared__ int s_lc[CAP];
    bool isbf = sniff_bf((const unsigned*)adjv);
    int bx = blockIdx.x;
    if (bx < NH * (NN / 64)) {                    // 128 GEMM blocks, dispatched first
        if (bx == 0 && threadIdx.x < NH * HIDD) vsum[threadIdx.x] = 0.f;
        int head = bx >> 6;
        int i0 = (bx & 63) * 64;
        float* Ch = hW + (size_t)head * NN * HIDD;
        if (isbf)
            hw_body<bf16>((const bf16*)h, (const bf16*)W1 + (size_t)head * IND * HIDD, Ch, i0, As, Bs);
        else
            hw_body<float>((const float*)h, (const float*)W1 + (size_t)head * IND * HIDD, Ch, i0, As, Bs);
        return;
    }
    int row = bx - NH * (NN / 64);                // 0 .. NH*NN-1
    if (threadIdx.x == 0) s_cnt = 0;
    __syncthreads();
    if (isbf) {                                   // bf16: row = 512 uint4 (8 elems)
        const uint4* a4 = reinterpret_cast<const uint4*>((const bf16*)adjv + (size_t)row * NN);
#pragma unroll
        for (int it = 0; it < 2; ++it) {
            int v = threadIdx.x + it * 256;
            uint4 d = a4[v];
            unsigned u[4] = {d.x, d.y, d.z, d.w};
            int base = v * 8;
#pragma unroll
            for (int w = 0; w < 4; ++w) {
                if (u[w] & 0xFFFFu) { int p = atomicAdd(&s_cnt, 1); if (p < CAP) s_lc[p] = base + 2 * w; }
                if (u[w] >> 16)     { int p = atomicAdd(&s_cnt, 1); if (p < CAP) s_lc[p] = base + 2 * w + 1; }
            }
        }
    } else {                                      // fp32: row = 1024 uint4 (4 elems)
        const uint4* a4 = reinterpret_cast<const uint4*>((const float*)adjv + (size_t)row * NN);
#pragma unroll
        for (int it = 0; it < 4; ++it) {
            int v = threadIdx.x + it * 256;
            uint4 d = a4[v];
            unsigned u[4] = {d.x, d.y, d.z, d.w};
            int base = v * 4;
#pragma unroll
            for (int w = 0; w < 4; ++w) {
                if (u[w]) { int p = atomicAdd(&s_cnt, 1); if (p < CAP) s_lc[p] = base + w; }
            }
        }
    }
    __syncthreads();
    int c = s_cnt; if (c > CAP) c = CAP;
    if (threadIdx.x == 0) deg[row] = c;
    int* oc = cols + (size_t)row * CAP;
    for (int k = threadIdx.x; k < c; k += 256) oc[k] = s_lc[k];
}

// ---------- K2: x-tile (sparse agg + relu) in LDS, then Q/K/V GEMMs + vsum ----------
// grid: 256 blocks = 128 tiles of 32 nodes x 2 heads, 256 threads
__global__ void __launch_bounds__(256) k2_x_qkv(const float* __restrict__ hW,
                                                const void* __restrict__ b1,
                                                const void* Wq, const void* bq,
                                                const void* Wk, const void* bk,
                                                const void* Wv, const void* bv,
                                                const void* __restrict__ adjv,
                                                const int* __restrict__ deg,
                                                const int* __restrict__ cols,
                                                float* Q, float* K, float* V,
                                                float* __restrict__ vsum) {
    bool isbf = sniff_bf((const unsigned*)adjv);
    int head = blockIdx.x >> 7;
    int i0 = (blockIdx.x & 127) * 32;
    __shared__ __align__(16) float xs[HIDD][36];     // [k][rowInTile], padded
    __shared__ __align__(16) float Ws[3][HIDD][68];  // [z][k][col]
    __shared__ float vred[HIDD];
    int tid = threadIdx.x;
    int t  = tid & 63;       // feature index
    int wv = tid >> 6;       // wave id 0..3
    const float* hWh = hW + (size_t)head * NN * HIDD;

    // phase A: x[i][t] = relu(b1 + sum_neighbors hW), stored transposed xs[t][i]
    float bb1 = ldf(b1, head * HIDD + t, isbf);
#pragma unroll
    for (int rr = 0; rr < 8; ++rr) {
        int n = i0 + rr * 4 + wv;
        int r = head * NN + n;
        int d = deg[r];
        const int* cl = cols + (size_t)r * CAP;
        float acc = bb1;
        for (int e = 0; e < d; ++e) acc += hWh[(size_t)cl[e] * HIDD + t];
        xs[t][rr * 4 + wv] = fmaxf(acc, 0.f);
    }
    // stage W for q,k,v: 64 x 64 each
    {
        int kb = tid >> 2;
        int cp = (tid & 3) * 16;
        const void* Wz[3] = {Wq, Wk, Wv};
#pragma unroll
        for (int z = 0; z < 3; ++z) {
            size_t base = (size_t)head * HIDD * HIDD + (size_t)kb * HIDD + cp;
            float t8[8];
            load8f(Wz[z], base, isbf, t8);
#pragma unroll
            for (int j = 0; j < 8; ++j) Ws[z][kb][cp + j] = t8[j];
            load8f(Wz[z], base + 8, isbf, t8);
#pragma unroll
            for (int j = 0; j < 8; ++j) Ws[z][kb][cp + 8 + j] = t8[j];
        }
    }
    if (tid < HIDD) vred[tid] = 0.f;
    __syncthreads();

    // phase C: out[z][i][c] = sum_k xs[k][i] * Ws[z][k][c] + b_z[c]
    int r0 = (tid >> 4) * 2;     // 2 rows
    int c0 = (tid & 15) * 4;     // 4 cols
    float acc[3][2][4] = {};
#pragma unroll 4
    for (int k = 0; k < HIDD; ++k) {
        float a0 = xs[k][r0], a1 = xs[k][r0 + 1];
#pragma unroll
        for (int z = 0; z < 3; ++z) {
            float4 w4 = *reinterpret_cast<const float4*>(&Ws[z][k][c0]);
            float wb[4] = {w4.x, w4.y, w4.z, w4.w};
#pragma unroll
            for (int ib = 0; ib < 4; ++ib) {
                acc[z][0][ib] = fmaf(a0, wb[ib], acc[z][0][ib]);
                acc[z][1][ib] = fmaf(a1, wb[ib], acc[z][1][ib]);
            }
        }
    }
    const void* bz3[3] = {bq, bk, bv};
    float* C3[3] = {Q + (size_t)head * NN * HIDD, K + (size_t)head * NN * HIDD,
                    V + (size_t)head * NN * HIDD};
    float bzv[4];
#pragma unroll
    for (int z = 0; z < 3; ++z) {
#pragma unroll
        for (int ib = 0; ib < 4; ++ib) bzv[ib] = ldf(bz3[z], head * HIDD + c0 + ib, isbf);
#pragma unroll
        for (int ia = 0; ia < 2; ++ia)
            *reinterpret_cast<float4*>(C3[z] + (size_t)(i0 + r0 + ia) * HIDD + c0) =
                make_float4(acc[z][ia][0] + bzv[0], acc[z][ia][1] + bzv[1],
                            acc[z][ia][2] + bzv[2], acc[z][ia][3] + bzv[3]);
    }
    // vsum: column sums of V tile (bias counted once per row: 2 rows/thread)
#pragma unroll
    for (int ib = 0; ib < 4; ++ib) bzv[ib] = ldf(bz3[2], head * HIDD + c0 + ib, isbf);
#pragma unroll
    for (int ib = 0; ib < 4; ++ib)
        atomicAdd(&vred[c0 + ib], acc[2][0][ib] + acc[2][1][ib] + 2.f * bzv[ib]);
    __syncthreads();
    if (tid < HIDD) atomicAdd(&vsum[head * HIDD + tid], vred[tid]);
}

// ---------- K3: per-node masked-softmax attention + head-sum + classifier ----------
__global__ void __launch_bounds__(256) k_attn(const float* __restrict__ Q,
                                              const float* __restrict__ Km,
                                              const float* __restrict__ V,
                                              const float* __restrict__ vsum,
                                              const int* __restrict__ deg,
                                              const int* __restrict__ cols,
                                              const void* __restrict__ predW,
                                              const void* __restrict__ predb,
                                              const void* __restrict__ adjv,
                                              void* __restrict__ outv) {
    bool isbf = sniff_bf((const unsigned*)adjv);
    int wid = threadIdx.x >> 6;
    int t   = threadIdx.x & 63;
    int i   = blockIdx.x * 4 + wid;
    __shared__ __align__(16) float qs[4][64];
    __shared__ float wgt[4][CAP];
    __shared__ int   cs[4][CAP];
    __shared__ float p2s[4][64];
    float p2 = 0.f;

    for (int h = 0; h < NH; ++h) {
        int r = h * NN + i;
        int d = deg[r];
        const int* cl   = cols + (size_t)r * CAP;
        const float* Qh = Q + (size_t)h * NN * HIDD;
        const float* Kh = Km + (size_t)h * NN * HIDD;
        const float* Vh = V + (size_t)h * NN * HIDD;
        qs[wid][t] = Qh[(size_t)i * HIDD + t];
        for (int e = t; e < d; e += 64) cs[wid][e] = cl[e];

        float s0 = 0.f, s1 = 0.f;
        float lmax = 0.f;                         // masked entries are exactly 0
        const float4* q4 = reinterpret_cast<const float4*>(qs[wid]);
        if (t < d) {
            const float4* K4 = reinterpret_cast<const float4*>(Kh + (size_t)cs[wid][t] * HIDD);
            float s = 0.f;
#pragma unroll 4
            for (int k = 0; k < 16; ++k) {
                float4 kv = K4[k]; float4 qv = q4[k];
                s += qv.x * kv.x + qv.y * kv.y + qv.z * kv.z + qv.w * kv.w;
            }
            s0 = s; lmax = fmaxf(lmax, s);
        }
        if (t + 64 < d) {
            const float4* K4 = reinterpret_cast<const float4*>(Kh + (size_t)cs[wid][t + 64] * HIDD);
            float s = 0.f;
#pragma unroll 4
            for (int k = 0; k < 16; ++k) {
                float4 kv = K4[k]; float4 qv = q4[k];
                s += qv.x * kv.x + qv.y * kv.y + qv.z * kv.z + qv.w * kv.w;
            }
            s1 = s; lmax = fmaxf(lmax, s);
        }
#pragma unroll
        for (int off = 32; off; off >>= 1) lmax = fmaxf(lmax, __shfl_xor(lmax, off));
        float m  = lmax;
        float eb = __expf(-m);                    // background weight
        float lsum = 0.f;
        if (t < d)      { float w = __expf(s0 - m); lsum += w; wgt[wid][t] = w - eb; }
        if (t + 64 < d) { float w = __expf(s1 - m); lsum += w; wgt[wid][t + 64] = w - eb; }
#pragma unroll
        for (int off = 32; off; off >>= 1) lsum += __shfl_xor(lsum, off);
        float Z = lsum + (float)(NN - d) * eb;    // row-sum==1 -> gcn_norm identity
        float c = 1.f / Z;

        float acc = eb * vsum[h * HIDD + t];
        for (int e = 0; e < d; ++e) acc += wgt[wid][e] * Vh[(size_t)cs[wid][e] * HIDD + t];
        p2 += fmaxf(acc * c, 0.f);                // relu(att @ V); beta==1 -> sum heads
    }

    p2s[wid][t] = p2;
    if (t < OUTD) {
        float a = ldf(predb, t, isbf);
#pragma unroll 8
        for (int k = 0; k < HIDD; ++k) a += p2s[wid][k] * ldf(predW, k * OUTD + t, isbf);
        float mx = a;
#pragma unroll
        for (int off = 4; off; off >>= 1) mx = fmaxf(mx, __shfl_xor(mx, off));
        float e = __expf(a - mx);
        float s = e;
#pragma unroll
        for (int off = 4; off; off >>= 1) s += __shfl_xor(s, off);
        float v = e / s;
        if (isbf) ((bf16*)outv)[(size_t)i * OUTD + t] = __float2bfloat16(v);
        else      ((float*)outv)[(size_t)i * OUTD + t] = v;
    }
}

extern "C" void kernel_launch(void* const* d_in, const int* in_sizes, int n_in,
                              void* d_out, int out_size, void* d_ws, size_t ws_size,
                              hipStream_t stream) {
    const void* adj = d_in[1];
    // d_in[10..12] = sem_W1/sem_b1/sem_W2 — provably unused (softmax over size-1 axis => beta = 1)

    char* w = (char*)d_ws;
    int*   deg  = (int*)w;                        w += (size_t)NH * NN * 4;
    int*   cols = (int*)w;                        w += (size_t)NH * NN * CAP * 4;
    float* hW   = (float*)w;                      w += (size_t)NH * NN * HIDD * 4;
    float* Q    = (float*)w;                      w += (size_t)NH * NN * HIDD * 4;
    float* K    = (float*)w;                      w += (size_t)NH * NN * HIDD * 4;
    float* V    = (float*)w;                      w += (size_t)NH * NN * HIDD * 4;
    float* vsum = (float*)w;                      w += (size_t)NH * HIDD * 4;

    k1_csr_hw<<<NH * (NN / 64) + NH * NN, 256, 0, stream>>>(d_in[0], d_in[2], adj,
                                                            deg, cols, hW, vsum);
    k2_x_qkv <<<NH * (NN / 32), 256, 0, stream>>>(hW, d_in[3], d_in[4], d_in[5], d_in[6],
                                                  d_in[7], d_in[8], d_in[9], adj,
                                                  deg, cols, Q, K, V, vsum);
    k_attn   <<<NN / 4, 256, 0, stream>>>(Q, K, V, vsum, deg, cols, d_in[13], d_in[14],
                                          adj, d_out);
}

// Round 5
// 255.020 us; speedup vs baseline: 1.2031x; 1.2031x over previous
//
#include <hip/hip_runtime.h>
#include <hip/hip_bf16.h>

#define NN   4096
#define IND  512
#define HIDD 64
#define OUTD 8
#define NH   2
#define CAP  128

using bf16 = __hip_bfloat16;

__device__ __forceinline__ float b2f(bf16 v) { return __bfloat162float(v); }

// adj diagonal is all ones. word0: fp32 -> 1.0f (low16==0); bf16 -> low16==0x3F80.
__device__ __forceinline__ bool sniff_bf(const unsigned* __restrict__ adjw) {
    return (adjw[0] & 0xFFFFu) == 0x3F80u;
}
__device__ __forceinline__ float ldf(const void* p, int i, bool isbf) {
    return isbf ? b2f(((const bf16*)p)[i]) : ((const float*)p)[i];
}
// load 8 consecutive elements (16B-aligned offset) as fp32
__device__ __forceinline__ void load8f(const void* p, size_t off, bool isbf, float* o) {
    if (isbf) {
        uint4 d = *reinterpret_cast<const uint4*>((const bf16*)p + off);
        unsigned u[4] = {d.x, d.y, d.z, d.w};
#pragma unroll
        for (int w = 0; w < 4; ++w) {
            o[2 * w]     = __uint_as_float(u[w] << 16);
            o[2 * w + 1] = __uint_as_float(u[w] & 0xFFFF0000u);
        }
    } else {
        const float* q = (const float*)p + off;
        float4 a = *reinterpret_cast<const float4*>(q);
        float4 b = *reinterpret_cast<const float4*>(q + 4);
        o[0] = a.x; o[1] = a.y; o[2] = a.z; o[3] = a.w;
        o[4] = b.x; o[5] = b.y; o[6] = b.z; o[7] = b.w;
    }
}
__device__ __forceinline__ void load8_f32(const float* q, float* o) {
    float4 a = *reinterpret_cast<const float4*>(q);
    float4 b = *reinterpret_cast<const float4*>(q + 4);
    o[0] = a.x; o[1] = a.y; o[2] = a.z; o[3] = a.w;
    o[4] = b.x; o[5] = b.y; o[6] = b.z; o[7] = b.w;
}

// ---------- h @ W1 : [64 x 512] * [512 x 64] ----------
template <typename T>
__device__ __forceinline__ void hw_body(const T* __restrict__ A,
                                        const T* __restrict__ B,
                                        float* __restrict__ C, int i0,
                                        float (*As)[68], float (*Bs)[68]) {
    int tid = threadIdx.x;
    int r0 = (tid >> 4) * 4;
    int c0 = (tid & 15) * 4;
    float acc[4][4] = {};
    for (int kc = 0; kc < IND; kc += 32) {
        {   // stage A: 64 rows x 32 k
            int row = tid >> 2;
            int kp  = (tid & 3) * 8;
            float t8[8];
            load8f((const void*)A, (size_t)(i0 + row) * IND + kc + kp, sizeof(T) == 2, t8);
#pragma unroll
            for (int j = 0; j < 8; ++j) As[kp + j][row] = t8[j];
        }
        {   // stage B: 32 k x 64 cols
            int kb = tid >> 3;
            int cp = (tid & 7) * 8;
            float t8[8];
            load8f((const void*)B, (size_t)(kc + kb) * HIDD + cp, sizeof(T) == 2, t8);
#pragma unroll
            for (int j = 0; j < 8; ++j) Bs[kb][cp + j] = t8[j];
        }
        __syncthreads();
#pragma unroll 8
        for (int k = 0; k < 32; ++k) {
            float4 av = *reinterpret_cast<const float4*>(&As[k][r0]);
            float4 bv = *reinterpret_cast<const float4*>(&Bs[k][c0]);
            float aa[4] = {av.x, av.y, av.z, av.w};
            float bb[4] = {bv.x, bv.y, bv.z, bv.w};
#pragma unroll
            for (int ia = 0; ia < 4; ++ia)
#pragma unroll
                for (int ib = 0; ib < 4; ++ib)
                    acc[ia][ib] = fmaf(aa[ia], bb[ib], acc[ia][ib]);
        }
        __syncthreads();
    }
#pragma unroll
    for (int ia = 0; ia < 4; ++ia)
        *reinterpret_cast<float4*>(C + (size_t)(i0 + r0 + ia) * HIDD + c0) =
            make_float4(acc[ia][0], acc[ia][1], acc[ia][2], acc[ia][3]);
}

// ---------- K1: blocks [0,128) compute hW tiles; blocks [128,8320) build CSR ----------
__global__ void __launch_bounds__(256) k1_csr_hw(const void* __restrict__ h,
                                                 const void* __restrict__ W1,
                                                 const void* __restrict__ adjv,
                                                 int* __restrict__ deg,
                                                 int* __restrict__ cols,
                                                 float* __restrict__ hW,
                                                 float* __restrict__ vsum) {
    __shared__ __align__(16) float As[32][68];
    __shared__ __align__(16) float Bs[32][68];
    __shared__ int s_cnt;
    __shared__ int s_lc[CAP];
    bool isbf = sniff_bf((const unsigned*)adjv);
    int bx = blockIdx.x;
    if (bx < NH * (NN / 64)) {                    // 128 GEMM blocks, dispatched first
        if (bx == 0 && threadIdx.x < NH * HIDD) vsum[threadIdx.x] = 0.f;
        int head = bx >> 6;
        int i0 = (bx & 63) * 64;
        float* Ch = hW + (size_t)head * NN * HIDD;
        if (isbf)
            hw_body<bf16>((const bf16*)h, (const bf16*)W1 + (size_t)head * IND * HIDD, Ch, i0, As, Bs);
        else
            hw_body<float>((const float*)h, (const float*)W1 + (size_t)head * IND * HIDD, Ch, i0, As, Bs);
        return;
    }
    int row = bx - NH * (NN / 64);                // 0 .. NH*NN-1
    if (threadIdx.x == 0) s_cnt = 0;
    __syncthreads();
    if (isbf) {                                   // bf16: row = 512 uint4 (8 elems)
        const uint4* a4 = reinterpret_cast<const uint4*>((const bf16*)adjv + (size_t)row * NN);
#pragma unroll
        for (int it = 0; it < 2; ++it) {
            int v = threadIdx.x + it * 256;
            uint4 d = a4[v];
            unsigned u[4] = {d.x, d.y, d.z, d.w};
            int base = v * 8;
#pragma unroll
            for (int w = 0; w < 4; ++w) {
                if (u[w] & 0xFFFFu) { int p = atomicAdd(&s_cnt, 1); if (p < CAP) s_lc[p] = base + 2 * w; }
                if (u[w] >> 16)     { int p = atomicAdd(&s_cnt, 1); if (p < CAP) s_lc[p] = base + 2 * w + 1; }
            }
        }
    } else {                                      // fp32: row = 1024 uint4 (4 elems)
        const uint4* a4 = reinterpret_cast<const uint4*>((const float*)adjv + (size_t)row * NN);
#pragma unroll
        for (int it = 0; it < 4; ++it) {
            int v = threadIdx.x + it * 256;
            uint4 d = a4[v];
            unsigned u[4] = {d.x, d.y, d.z, d.w};
            int base = v * 4;
#pragma unroll
            for (int w = 0; w < 4; ++w) {
                if (u[w]) { int p = atomicAdd(&s_cnt, 1); if (p < CAP) s_lc[p] = base + w; }
            }
        }
    }
    __syncthreads();
    int c = s_cnt; if (c > CAP) c = CAP;
    if (threadIdx.x == 0) deg[row] = c;
    int* oc = cols + (size_t)row * CAP;
    for (int k = threadIdx.x; k < c; k += 256) oc[k] = s_lc[k];
}

// ---------- K2: x = relu(adj @ hW + b1), 4-way unrolled gather ----------
__global__ void k_aggx(const float* __restrict__ hW, const void* __restrict__ b1,
                       const void* __restrict__ adjv,
                       const int* __restrict__ deg, const int* __restrict__ cols,
                       float* __restrict__ x) {
    bool isbf = sniff_bf((const unsigned*)adjv);
    int h = blockIdx.y;
    int i = blockIdx.x * 4 + threadIdx.y;
    int t = threadIdx.x;
    const float* hWh = hW + (size_t)h * NN * HIDD;
    int r = h * NN + i;
    int d = deg[r];
    const int* cl = cols + (size_t)r * CAP;
    float acc = ldf(b1, h * HIDD + t, isbf);
    int e = 0;
    for (; e + 4 <= d; e += 4) {                  // 4 independent loads in flight
        int c0 = cl[e], c1 = cl[e + 1], c2 = cl[e + 2], c3 = cl[e + 3];
        float v0 = hWh[(size_t)c0 * HIDD + t];
        float v1 = hWh[(size_t)c1 * HIDD + t];
        float v2 = hWh[(size_t)c2 * HIDD + t];
        float v3 = hWh[(size_t)c3 * HIDD + t];
        acc += (v0 + v1) + (v2 + v3);
    }
    for (; e < d; ++e) acc += hWh[(size_t)cl[e] * HIDD + t];
    x[(size_t)r * HIDD + t] = fmaxf(acc, 0.f);
}

// ---------- K3: Q/K/V = x @ W + b, 64x64 tiles; V blocks also reduce vsum ----------
__global__ void __launch_bounds__(256) k_qkv(const float* __restrict__ x,
                                             const void* Wq, const void* bq,
                                             const void* Wk, const void* bk,
                                             const void* Wv, const void* bv,
                                             const void* __restrict__ adjv,
                                             float* Q, float* K, float* V,
                                             float* __restrict__ vsum) {
    bool isbf = sniff_bf((const unsigned*)adjv);
    int head = blockIdx.y, z = blockIdx.z;
    int i0 = blockIdx.x * 64;
    const void* W  = (z == 0) ? Wq : (z == 1) ? Wk : Wv;
    const void* bb = (z == 0) ? bq : (z == 1) ? bk : bv;
    float* C       = ((z == 0) ? Q : (z == 1) ? K : V) + (size_t)head * NN * HIDD;
    const float* xh = x + (size_t)head * NN * HIDD;

    __shared__ __align__(16) float As[64][68];   // [k][row] of x tile
    __shared__ __align__(16) float Bs[64][68];   // [k][col] of W
    int tid = threadIdx.x;
    {   // stage x tile: 64 rows x 64 k (fp32)
        int row = tid >> 2;
        int kp  = (tid & 3) * 16;
        float t8[8];
        load8_f32(xh + (size_t)(i0 + row) * HIDD + kp, t8);
#pragma unroll
        for (int j = 0; j < 8; ++j) As[kp + j][row] = t8[j];
        load8_f32(xh + (size_t)(i0 + row) * HIDD + kp + 8, t8);
#pragma unroll
        for (int j = 0; j < 8; ++j) As[kp + 8 + j][row] = t8[j];
    }
    {   // stage W: 64 k x 64 cols (native dtype)
        int kb = tid >> 2;
        int cp = (tid & 3) * 16;
        size_t base = (size_t)head * HIDD * HIDD + (size_t)kb * HIDD + cp;
        float t8[8];
        load8f(W, base, isbf, t8);
#pragma unroll
        for (int j = 0; j < 8; ++j) Bs[kb][cp + j] = t8[j];
        load8f(W, base + 8, isbf, t8);
#pragma unroll
        for (int j = 0; j < 8; ++j) Bs[kb][cp + 8 + j] = t8[j];
    }
    __syncthreads();

    int r0 = (tid >> 4) * 4;
    int c0 = (tid & 15) * 4;
    float acc[4][4] = {};
#pragma unroll 8
    for (int k = 0; k < 64; ++k) {
        float4 av = *reinterpret_cast<const float4*>(&As[k][r0]);
        float4 bv4 = *reinterpret_cast<const float4*>(&Bs[k][c0]);
        float aa[4] = {av.x, av.y, av.z, av.w};
        float bbv[4] = {bv4.x, bv4.y, bv4.z, bv4.w};
#pragma unroll
        for (int ia = 0; ia < 4; ++ia)
#pragma unroll
            for (int ib = 0; ib < 4; ++ib)
                acc[ia][ib] = fmaf(aa[ia], bbv[ib], acc[ia][ib]);
    }
    float bz[4];
#pragma unroll
    for (int b = 0; b < 4; ++b) bz[b] = ldf(bb, head * HIDD + c0 + b, isbf);
#pragma unroll
    for (int ia = 0; ia < 4; ++ia)
        *reinterpret_cast<float4*>(C + (size_t)(i0 + r0 + ia) * HIDD + c0) =
            make_float4(acc[ia][0] + bz[0], acc[ia][1] + bz[1],
                        acc[ia][2] + bz[2], acc[ia][3] + bz[3]);

    if (z == 2) {   // column-sum of this V tile -> vsum[head]
        float vpart[4];
#pragma unroll
        for (int ib = 0; ib < 4; ++ib)
            vpart[ib] = acc[0][ib] + acc[1][ib] + acc[2][ib] + acc[3][ib];
        __syncthreads();
        if (tid < HIDD) As[0][tid] = 0.f;
        __syncthreads();
        // each thread covers 4 rows for its 4 cols -> bias contributes 4*bz per thread
#pragma unroll
        for (int ib = 0; ib < 4; ++ib)
            atomicAdd(&As[0][c0 + ib], vpart[ib] + 4.f * bz[ib]);
        __syncthreads();
        if (tid < HIDD) atomicAdd(&vsum[head * HIDD + tid], As[0][tid]);
    }
}

// ---------- K4: per-node masked-softmax attention + head-sum + classifier ----------
// one wave per node, 4 nodes per block, zero barriers (wave-private LDS slices)
__global__ void __launch_bounds__(256) k_attn(const float* __restrict__ Q,
                                              const float* __restrict__ Km,
                                              const float* __restrict__ V,
                                              const float* __restrict__ vsum,
                                              const int* __restrict__ deg,
                                              const int* __restrict__ cols,
                                              const void* __restrict__ predW,
                                              const void* __restrict__ predb,
                                              const void* __restrict__ adjv,
                                              void* __restrict__ outv) {
    bool isbf = sniff_bf((const unsigned*)adjv);
    int wid = threadIdx.x >> 6;
    int t   = threadIdx.x & 63;
    int i   = blockIdx.x * 4 + wid;
    __shared__ __align__(16) float qs[4][64];
    __shared__ float wgt[4][CAP];
    __shared__ int   cs[4][CAP];
    __shared__ float p2s[4][64];
    float p2 = 0.f;

    for (int h = 0; h < NH; ++h) {
        int r = h * NN + i;
        int d = deg[r];
        const int* cl   = cols + (size_t)r * CAP;
        const float* Qh = Q + (size_t)h * NN * HIDD;
        const float* Kh = Km + (size_t)h * NN * HIDD;
        const float* Vh = V + (size_t)h * NN * HIDD;
        qs[wid][t] = Qh[(size_t)i * HIDD + t];
        for (int e = t; e < d; e += 64) cs[wid][e] = cl[e];

        float s0 = 0.f, s1 = 0.f;
        float lmax = 0.f;                         // masked entries are exactly 0
        const float4* q4 = reinterpret_cast<const float4*>(qs[wid]);
        if (t < d) {
            const float4* K4 = reinterpret_cast<const float4*>(Kh + (size_t)cs[wid][t] * HIDD);
            float s = 0.f;
#pragma unroll 4
            for (int k = 0; k < 16; ++k) {
                float4 kv = K4[k]; float4 qv = q4[k];
                s += qv.x * kv.x + qv.y * kv.y + qv.z * kv.z + qv.w * kv.w;
            }
            s0 = s; lmax = fmaxf(lmax, s);
        }
        if (t + 64 < d) {
            const float4* K4 = reinterpret_cast<const float4*>(Kh + (size_t)cs[wid][t + 64] * HIDD);
            float s = 0.f;
#pragma unroll 4
            for (int k = 0; k < 16; ++k) {
                float4 kv = K4[k]; float4 qv = q4[k];
                s += qv.x * kv.x + qv.y * kv.y + qv.z * kv.z + qv.w * kv.w;
            }
            s1 = s; lmax = fmaxf(lmax, s);
        }
#pragma unroll
        for (int off = 32; off; off >>= 1) lmax = fmaxf(lmax, __shfl_xor(lmax, off));
        float m  = lmax;
        float eb = __expf(-m);                    // background weight
        float lsum = 0.f;
        if (t < d)      { float w = __expf(s0 - m); lsum += w; wgt[wid][t] = w - eb; }
        if (t + 64 < d) { float w = __expf(s1 - m); lsum += w; wgt[wid][t + 64] = w - eb; }
#pragma unroll
        for (int off = 32; off; off >>= 1) lsum += __shfl_xor(lsum, off);
        float Z = lsum + (float)(NN - d) * eb;    // row-sum==1 -> gcn_norm identity
        float c = 1.f / Z;

        float acc = eb * vsum[h * HIDD + t];
        int e = 0;
        for (; e + 4 <= d; e += 4) {              // 4 independent V loads in flight
            float w0 = wgt[wid][e], w1 = wgt[wid][e + 1];
            float w2 = wgt[wid][e + 2], w3 = wgt[wid][e + 3];
            int c0 = cs[wid][e], c1 = cs[wid][e + 1];
            int c2 = cs[wid][e + 2], c3 = cs[wid][e + 3];
            float v0 = Vh[(size_t)c0 * HIDD + t];
            float v1 = Vh[(size_t)c1 * HIDD + t];
            float v2 = Vh[(size_t)c2 * HIDD + t];
            float v3 = Vh[(size_t)c3 * HIDD + t];
            acc += w0 * v0 + w1 * v1 + w2 * v2 + w3 * v3;
        }
        for (; e < d; ++e) acc += wgt[wid][e] * Vh[(size_t)cs[wid][e] * HIDD + t];
        p2 += fmaxf(acc * c, 0.f);                // relu(att @ V); beta==1 -> sum heads
    }

    p2s[wid][t] = p2;
    if (t < OUTD) {
        float a = ldf(predb, t, isbf);
#pragma unroll 8
        for (int k = 0; k < HIDD; ++k) a += p2s[wid][k] * ldf(predW, k * OUTD + t, isbf);
        float mx = a;
#pragma unroll
        for (int off = 4; off; off >>= 1) mx = fmaxf(mx, __shfl_xor(mx, off));
        float e = __expf(a - mx);
        float s = e;
#pragma unroll
        for (int off = 4; off; off >>= 1) s += __shfl_xor(s, off);
        float v = e / s;
        if (isbf) ((bf16*)outv)[(size_t)i * OUTD + t] = __float2bfloat16(v);
        else      ((float*)outv)[(size_t)i * OUTD + t] = v;
    }
}

extern "C" void kernel_launch(void* const* d_in, const int* in_sizes, int n_in,
                              void* d_out, int out_size, void* d_ws, size_t ws_size,
                              hipStream_t stream) {
    const void* adj = d_in[1];
    // d_in[10..12] = sem_W1/sem_b1/sem_W2 — provably unused (softmax over size-1 axis => beta = 1)

    char* w = (char*)d_ws;
    int*   deg  = (int*)w;                        w += (size_t)NH * NN * 4;
    int*   cols = (int*)w;                        w += (size_t)NH * NN * CAP * 4;
    float* hW   = (float*)w;                      w += (size_t)NH * NN * HIDD * 4;
    float* x    = (float*)w;                      w += (size_t)NH * NN * HIDD * 4;
    float* Q    = (float*)w;                      w += (size_t)NH * NN * HIDD * 4;
    float* K    = (float*)w;                      w += (size_t)NH * NN * HIDD * 4;
    float* V    = (float*)w;                      w += (size_t)NH * NN * HIDD * 4;
    float* vsum = (float*)w;                      w += (size_t)NH * HIDD * 4;

    k1_csr_hw<<<NH * (NN / 64) + NH * NN, 256, 0, stream>>>(d_in[0], d_in[2], adj,
                                                            deg, cols, hW, vsum);
    k_aggx   <<<dim3(NN / 4, NH), dim3(64, 4), 0, stream>>>(hW, d_in[3], adj, deg, cols, x);
    k_qkv    <<<dim3(NN / 64, NH, 3), 256, 0, stream>>>(x, d_in[4], d_in[5], d_in[6], d_in[7],
                                                        d_in[8], d_in[9], adj, Q, K, V, vsum);
    k_attn   <<<NN / 4, 256, 0, stream>>>(Q, K, V, vsum, deg, cols, d_in[13], d_in[14],
                                          adj, d_out);
}